// Round 2
// baseline (706.867 us; speedup 1.0000x reference)
//
#include <hip/hip_runtime.h>

#define NROWS 2048
#define MCOLS 2048

// ---- d_ws layout (float offsets) ----
#define OFF_AF 0                        // 2048 x 20 (padded A rows, fluid)
#define OFF_AS (OFF_AF + NROWS * 20)    // 2048 x 20 (solid)
#define OFF_BF (OFF_AS + NROWS * 20)    // 2048 x 18
#define OFF_BS (OFF_BF + NROWS * 18)    // 2048 x 18
#define OFF_WP (OFF_BS + NROWS * 18)    // 504 packed tail weights
#define OFF_CF (OFF_WP + 512)           // int counts, fluid, 2048
#define OFF_CS (OFF_CF + NROWS)         // int counts, solid, 2048
#define OFF_LISTS (OFF_CS + NROWS)      // u16 lists region
#define LF_CAP ((size_t)NROWS * MCOLS)  // capacity of fluid list region in u16

// packed tail-weight layout (within OFF_WP), fluid then solid (+252)
#define WP_W1 0
#define WP_B1 162
#define WP_W2 171
#define WP_B2 225
#define WP_W3 231
#define WP_B3 249
#define WP_SOLID 252

__device__ __forceinline__ float fast_tanh(float x) {
    // tanh(x) = 1 - 2/(1 + e^{2x}),  e^{2x} = 2^{x * 2*log2(e)}
    float t = __builtin_amdgcn_exp2f(x * 2.8853900817779268f);
    return 1.0f - 2.0f * __builtin_amdgcn_rcpf(1.0f + t);
}

// 18 -> 9 -> 6 -> 3 tail; input pre-activation = arow[j] + sB[j]
__device__ __forceinline__ void mlp_eval(const float* __restrict__ arow,
                                         const float* __restrict__ sB,
                                         const float* __restrict__ sW,
                                         float o[3]) {
    float a[20];
#pragma unroll
    for (int t = 0; t < 5; ++t)
        ((float4*)a)[t] = ((const float4*)arow)[t];
    float h[18];
#pragma unroll
    for (int j = 0; j < 18; ++j) h[j] = fast_tanh(a[j] + sB[j]);
    float g[9];
#pragma unroll
    for (int o9 = 0; o9 < 9; ++o9) g[o9] = sW[WP_B1 + o9];
#pragma unroll
    for (int j = 0; j < 18; ++j) {
        float hj = h[j];
#pragma unroll
        for (int o9 = 0; o9 < 9; ++o9) g[o9] += hj * sW[WP_W1 + j * 9 + o9];
    }
#pragma unroll
    for (int o9 = 0; o9 < 9; ++o9) g[o9] = fast_tanh(g[o9]);
    float q[6];
#pragma unroll
    for (int o6 = 0; o6 < 6; ++o6) q[o6] = sW[WP_B2 + o6];
#pragma unroll
    for (int j = 0; j < 9; ++j) {
        float gj = g[j];
#pragma unroll
        for (int o6 = 0; o6 < 6; ++o6) q[o6] += gj * sW[WP_W2 + j * 6 + o6];
    }
#pragma unroll
    for (int o6 = 0; o6 < 6; ++o6) q[o6] = fast_tanh(q[o6]);
#pragma unroll
    for (int o3 = 0; o3 < 3; ++o3) o[o3] = sW[WP_B3 + o3];
#pragma unroll
    for (int j = 0; j < 6; ++j) {
        float qj = q[j];
#pragma unroll
        for (int o3 = 0; o3 < 3; ++o3) o[o3] += qj * sW[WP_W3 + j * 3 + o3];
    }
}

__global__ void prep_kernel(const int* __restrict__ index,
                            const float* __restrict__ data,
                            const float* __restrict__ wf0, const float* __restrict__ bf0,
                            const float* __restrict__ sw0, const float* __restrict__ sb0,
                            const float* __restrict__ wf1, const float* __restrict__ bf1,
                            const float* __restrict__ wf2, const float* __restrict__ bf2,
                            const float* __restrict__ wf3, const float* __restrict__ bf3,
                            const float* __restrict__ sw1, const float* __restrict__ sb1,
                            const float* __restrict__ sw2, const float* __restrict__ sb2,
                            const float* __restrict__ sw3, const float* __restrict__ sb3,
                            float* __restrict__ wsp) {
    int i = blockIdx.x * blockDim.x + threadIdx.x;
    if (i < NROWS) {
        float d[7], cen[7];
#pragma unroll
        for (int c = 0; c < 7; ++c) d[c] = data[i * 7 + c];
        int ci = index[i];
#pragma unroll
        for (int c = 0; c < 7; ++c) cen[c] = data[ci * 7 + c];
#pragma unroll
        for (int j = 0; j < 18; ++j) {
            float af = 0.f;
#pragma unroll
            for (int c = 0; c < 7; ++c) af += d[c] * wf0[c * 18 + j];
            float as = d[0] * sw0[0 * 18 + j] + d[1] * sw0[1 * 18 + j] + d[2] * sw0[2 * 18 + j];
            float bf = bf0[j], bs = sb0[j];
#pragma unroll
            for (int c = 0; c < 3; ++c) bf -= cen[c] * wf0[c * 18 + j];
#pragma unroll
            for (int c = 0; c < 4; ++c) bf += cen[3 + c] * wf0[(7 + c) * 18 + j];
#pragma unroll
            for (int c = 0; c < 3; ++c) bs -= cen[c] * sw0[c * 18 + j];
#pragma unroll
            for (int c = 0; c < 4; ++c) bs += cen[3 + c] * sw0[(3 + c) * 18 + j];
            wsp[OFF_AF + i * 20 + j] = af;
            wsp[OFF_AS + i * 20 + j] = as;
            wsp[OFF_BF + i * 18 + j] = bf;
            wsp[OFF_BS + i * 18 + j] = bs;
        }
        wsp[OFF_AF + i * 20 + 18] = 0.f; wsp[OFF_AF + i * 20 + 19] = 0.f;
        wsp[OFF_AS + i * 20 + 18] = 0.f; wsp[OFF_AS + i * 20 + 19] = 0.f;
    }
    if (blockIdx.x == 0) {
        int t = threadIdx.x;
        float* wp = wsp + OFF_WP;
        for (int k = t; k < 162; k += 256) wp[WP_W1 + k] = wf1[k];
        for (int k = t; k < 9;   k += 256) wp[WP_B1 + k] = bf1[k];
        for (int k = t; k < 54;  k += 256) wp[WP_W2 + k] = wf2[k];
        for (int k = t; k < 6;   k += 256) wp[WP_B2 + k] = bf2[k];
        for (int k = t; k < 18;  k += 256) wp[WP_W3 + k] = wf3[k];
        for (int k = t; k < 3;   k += 256) wp[WP_B3 + k] = bf3[k];
        for (int k = t; k < 162; k += 256) wp[WP_SOLID + WP_W1 + k] = sw1[k];
        for (int k = t; k < 9;   k += 256) wp[WP_SOLID + WP_B1 + k] = sb1[k];
        for (int k = t; k < 54;  k += 256) wp[WP_SOLID + WP_W2 + k] = sw2[k];
        for (int k = t; k < 6;   k += 256) wp[WP_SOLID + WP_B2 + k] = sb2[k];
        for (int k = t; k < 18;  k += 256) wp[WP_SOLID + WP_W3 + k] = sw3[k];
        for (int k = t; k < 3;   k += 256) wp[WP_SOLID + WP_B3 + k] = sb3[k];
    }
}

// One wave per row: build compacted column lists for fluid / solid.
__global__ __launch_bounds__(256)
void compact_kernel(const int* __restrict__ mask,
                    const float* __restrict__ data,
                    float* __restrict__ wsp) {
    const int lane = threadIdx.x & 63;
    const int n = blockIdx.x * 4 + (threadIdx.x >> 6);
    int* counts_f = (int*)(wsp + OFF_CF);
    int* counts_s = (int*)(wsp + OFF_CS);
    unsigned short* lf = (unsigned short*)(wsp + OFF_LISTS) + (size_t)n * MCOLS;
    unsigned short* ls = lf + LF_CAP;
    const int* mrow = mask + (size_t)n * MCOLS;
    int bf = 0, bs = 0;
    const unsigned long long ltmask = (1ull << lane) - 1ull;
#pragma unroll 1
    for (int it = 0; it < MCOLS / 64; ++it) {
        const int m = it * 64 + lane;
        const int mk = mrow[m];
        const float flag = data[m * 7 + 6];
        const bool af = mk && (flag > 0.f);
        const bool as = mk && (flag < 1.f);
        const unsigned long long balf = __ballot(af);
        const unsigned long long bals = __ballot(as);
        if (af) lf[bf + __popcll(balf & ltmask)] = (unsigned short)m;
        if (as) ls[bs + __popcll(bals & ltmask)] = (unsigned short)m;
        bf += __popcll(balf);
        bs += __popcll(bals);
    }
    if (lane == 0) { counts_f[n] = bf; counts_s[n] = bs; }
}

// One block per output row n; iterate that row's compacted lists.
__global__ __launch_bounds__(256, 4)
void main_kernel(const float* __restrict__ wsp, float* __restrict__ out) {
    const int n = blockIdx.x;
    const int tid = threadIdx.x;
    __shared__ float sW[504];
    __shared__ float sBf[18], sBs[18];
    __shared__ float red[3][4];
    for (int k = tid; k < 504; k += 256) sW[k] = wsp[OFF_WP + k];
    if (tid < 18) sBf[tid] = wsp[OFF_BF + n * 18 + tid];
    else if (tid < 36) sBs[tid - 18] = wsp[OFF_BS + n * 18 + (tid - 18)];
    __syncthreads();

    const int cf = ((const int*)(wsp + OFF_CF))[n];
    const int cs = ((const int*)(wsp + OFF_CS))[n];
    const unsigned short* lf = (const unsigned short*)(wsp + OFF_LISTS) + (size_t)n * MCOLS;
    const unsigned short* ls = lf + LF_CAP;

    float p0 = 0.f, p1 = 0.f, p2 = 0.f;
#pragma unroll 1
    for (int i = tid; i < cf; i += 256) {
        const int m = lf[i];
        float o[3];
        mlp_eval(wsp + OFF_AF + m * 20, sBf, sW, o);
        p0 += o[0]; p1 += o[1]; p2 += o[2];
    }
#pragma unroll 1
    for (int i = tid; i < cs; i += 256) {
        const int m = ls[i];
        float o[3];
        mlp_eval(wsp + OFF_AS + m * 20, sBs, sW + WP_SOLID, o);
        p0 += o[0]; p1 += o[1]; p2 += o[2];
    }

#pragma unroll
    for (int off = 32; off > 0; off >>= 1) {
        p0 += __shfl_xor(p0, off, 64);
        p1 += __shfl_xor(p1, off, 64);
        p2 += __shfl_xor(p2, off, 64);
    }
    const int wid = tid >> 6;
    if ((tid & 63) == 0) { red[0][wid] = p0; red[1][wid] = p1; red[2][wid] = p2; }
    __syncthreads();
    if (tid == 0) {
        float s0 = 0.f, s1 = 0.f, s2 = 0.f;
#pragma unroll
        for (int w = 0; w < 4; ++w) { s0 += red[0][w]; s1 += red[1][w]; s2 += red[2][w]; }
        out[n * 3 + 0] = s0; out[n * 3 + 1] = s1; out[n * 3 + 2] = s2;
    }
}

extern "C" void kernel_launch(void* const* d_in, const int* in_sizes, int n_in,
                              void* d_out, int out_size, void* d_ws, size_t ws_size,
                              hipStream_t stream) {
    const int*   mask  = (const int*)d_in[0];
    const int*   index = (const int*)d_in[1];
    const float* data  = (const float*)d_in[2];
    const float* wf0   = (const float*)d_in[3];
    const float* bf0   = (const float*)d_in[4];
    const float* wf1   = (const float*)d_in[5];
    const float* bf1   = (const float*)d_in[6];
    const float* wf2   = (const float*)d_in[7];
    const float* bf2   = (const float*)d_in[8];
    const float* wf3   = (const float*)d_in[9];
    const float* bf3   = (const float*)d_in[10];
    const float* sw0   = (const float*)d_in[11];
    const float* sb0   = (const float*)d_in[12];
    const float* sw1   = (const float*)d_in[13];
    const float* sb1   = (const float*)d_in[14];
    const float* sw2   = (const float*)d_in[15];
    const float* sb2   = (const float*)d_in[16];
    const float* sw3   = (const float*)d_in[17];
    const float* sb3   = (const float*)d_in[18];
    float* wsp = (float*)d_ws;
    float* out = (float*)d_out;

    prep_kernel<<<dim3(8), dim3(256), 0, stream>>>(
        index, data, wf0, bf0, sw0, sb0, wf1, bf1, wf2, bf2, wf3, bf3,
        sw1, sb1, sw2, sb2, sw3, sb3, wsp);
    compact_kernel<<<dim3(NROWS / 4), dim3(256), 0, stream>>>(mask, data, wsp);
    main_kernel<<<dim3(NROWS), dim3(256), 0, stream>>>(wsp, out);
}

// Round 3
// 174.427 us; speedup vs baseline: 4.0525x; 4.0525x over previous
//
#include <hip/hip_runtime.h>

#define NROWS 2048
#define MCOLS 2048

// ---- d_ws layout (float offsets) ----
#define OFF_AF 0                        // 2048 x 20 (padded A rows, fluid)
#define OFF_AS (OFF_AF + NROWS * 20)    // 2048 x 20 (solid)
#define OFF_BF (OFF_AS + NROWS * 20)    // 2048 x 18
#define OFF_BS (OFF_BF + NROWS * 18)    // 2048 x 18
#define OFF_WP (OFF_BS + NROWS * 18)    // 504 packed tail weights
#define OFF_CF (OFF_WP + 512)           // int counts, fluid, 2048
#define OFF_CS (OFF_CF + NROWS)         // int counts, solid, 2048
#define OFF_LISTS (OFF_CS + NROWS)      // u16 lists region
#define LF_CAP ((size_t)NROWS * MCOLS)  // capacity of fluid list region in u16

// packed tail-weight layout (within OFF_WP), fluid then solid (+252)
#define WP_W1 0
#define WP_B1 162
#define WP_W2 171
#define WP_B2 225
#define WP_W3 231
#define WP_B3 249
#define WP_SOLID 252

__device__ __forceinline__ float fast_tanh(float x) {
    float t = __builtin_amdgcn_exp2f(x * 2.8853900817779268f);
    return 1.0f - 2.0f * __builtin_amdgcn_rcpf(1.0f + t);
}

// ---- shared 18->9->6->3 tail, TWO evals per weight read ----
__device__ __forceinline__ void mlp_pair(const float* __restrict__ wsA,
                                         int m0, int m1,
                                         const float* __restrict__ sB,
                                         const float* __restrict__ sW,
                                         float& p0, float& p1, float& p2) {
    const float* r0 = wsA + m0 * 20;
    const float* r1 = wsA + m1 * 20;
    float4 P0 = *(const float4*)(r0);
    float4 P1 = *(const float4*)(r0 + 4);
    float4 P2 = *(const float4*)(r0 + 8);
    float4 P3 = *(const float4*)(r0 + 12);
    float2 P4 = *(const float2*)(r0 + 16);
    float4 Q0 = *(const float4*)(r1);
    float4 Q1 = *(const float4*)(r1 + 4);
    float4 Q2 = *(const float4*)(r1 + 8);
    float4 Q3 = *(const float4*)(r1 + 12);
    float2 Q4 = *(const float2*)(r1 + 16);
    float hA[18], hB[18];
    hA[0]  = fast_tanh(P0.x + sB[0]);  hB[0]  = fast_tanh(Q0.x + sB[0]);
    hA[1]  = fast_tanh(P0.y + sB[1]);  hB[1]  = fast_tanh(Q0.y + sB[1]);
    hA[2]  = fast_tanh(P0.z + sB[2]);  hB[2]  = fast_tanh(Q0.z + sB[2]);
    hA[3]  = fast_tanh(P0.w + sB[3]);  hB[3]  = fast_tanh(Q0.w + sB[3]);
    hA[4]  = fast_tanh(P1.x + sB[4]);  hB[4]  = fast_tanh(Q1.x + sB[4]);
    hA[5]  = fast_tanh(P1.y + sB[5]);  hB[5]  = fast_tanh(Q1.y + sB[5]);
    hA[6]  = fast_tanh(P1.z + sB[6]);  hB[6]  = fast_tanh(Q1.z + sB[6]);
    hA[7]  = fast_tanh(P1.w + sB[7]);  hB[7]  = fast_tanh(Q1.w + sB[7]);
    hA[8]  = fast_tanh(P2.x + sB[8]);  hB[8]  = fast_tanh(Q2.x + sB[8]);
    hA[9]  = fast_tanh(P2.y + sB[9]);  hB[9]  = fast_tanh(Q2.y + sB[9]);
    hA[10] = fast_tanh(P2.z + sB[10]); hB[10] = fast_tanh(Q2.z + sB[10]);
    hA[11] = fast_tanh(P2.w + sB[11]); hB[11] = fast_tanh(Q2.w + sB[11]);
    hA[12] = fast_tanh(P3.x + sB[12]); hB[12] = fast_tanh(Q3.x + sB[12]);
    hA[13] = fast_tanh(P3.y + sB[13]); hB[13] = fast_tanh(Q3.y + sB[13]);
    hA[14] = fast_tanh(P3.z + sB[14]); hB[14] = fast_tanh(Q3.z + sB[14]);
    hA[15] = fast_tanh(P3.w + sB[15]); hB[15] = fast_tanh(Q3.w + sB[15]);
    hA[16] = fast_tanh(P4.x + sB[16]); hB[16] = fast_tanh(Q4.x + sB[16]);
    hA[17] = fast_tanh(P4.y + sB[17]); hB[17] = fast_tanh(Q4.y + sB[17]);
    float gA[9], gB[9];
#pragma unroll
    for (int o = 0; o < 9; ++o) { float b = sW[WP_B1 + o]; gA[o] = b; gB[o] = b; }
#pragma unroll
    for (int j = 0; j < 18; ++j) {
        float a = hA[j], b = hB[j];
#pragma unroll
        for (int o = 0; o < 9; ++o) { float w = sW[WP_W1 + j * 9 + o]; gA[o] += a * w; gB[o] += b * w; }
    }
#pragma unroll
    for (int o = 0; o < 9; ++o) { gA[o] = fast_tanh(gA[o]); gB[o] = fast_tanh(gB[o]); }
    float qA[6], qB[6];
#pragma unroll
    for (int o = 0; o < 6; ++o) { float b = sW[WP_B2 + o]; qA[o] = b; qB[o] = b; }
#pragma unroll
    for (int j = 0; j < 9; ++j) {
        float a = gA[j], b = gB[j];
#pragma unroll
        for (int o = 0; o < 6; ++o) { float w = sW[WP_W2 + j * 6 + o]; qA[o] += a * w; qB[o] += b * w; }
    }
#pragma unroll
    for (int o = 0; o < 6; ++o) { qA[o] = fast_tanh(qA[o]); qB[o] = fast_tanh(qB[o]); }
    float oA0 = sW[WP_B3 + 0], oA1 = sW[WP_B3 + 1], oA2 = sW[WP_B3 + 2];
    float oB0 = oA0, oB1 = oA1, oB2 = oA2;
#pragma unroll
    for (int j = 0; j < 6; ++j) {
        float a = qA[j], b = qB[j];
        float w0 = sW[WP_W3 + j * 3 + 0], w1 = sW[WP_W3 + j * 3 + 1], w2 = sW[WP_W3 + j * 3 + 2];
        oA0 += a * w0; oA1 += a * w1; oA2 += a * w2;
        oB0 += b * w0; oB1 += b * w1; oB2 += b * w2;
    }
    p0 += oA0 + oB0; p1 += oA1 + oB1; p2 += oA2 + oB2;
}

// ---- single-eval version for odd tails ----
__device__ __forceinline__ void mlp_one(const float* __restrict__ wsA, int m,
                                        const float* __restrict__ sB,
                                        const float* __restrict__ sW,
                                        float& p0, float& p1, float& p2) {
    const float* r0 = wsA + m * 20;
    float4 P0 = *(const float4*)(r0);
    float4 P1 = *(const float4*)(r0 + 4);
    float4 P2 = *(const float4*)(r0 + 8);
    float4 P3 = *(const float4*)(r0 + 12);
    float2 P4 = *(const float2*)(r0 + 16);
    float h[18];
    h[0]  = fast_tanh(P0.x + sB[0]);  h[1]  = fast_tanh(P0.y + sB[1]);
    h[2]  = fast_tanh(P0.z + sB[2]);  h[3]  = fast_tanh(P0.w + sB[3]);
    h[4]  = fast_tanh(P1.x + sB[4]);  h[5]  = fast_tanh(P1.y + sB[5]);
    h[6]  = fast_tanh(P1.z + sB[6]);  h[7]  = fast_tanh(P1.w + sB[7]);
    h[8]  = fast_tanh(P2.x + sB[8]);  h[9]  = fast_tanh(P2.y + sB[9]);
    h[10] = fast_tanh(P2.z + sB[10]); h[11] = fast_tanh(P2.w + sB[11]);
    h[12] = fast_tanh(P3.x + sB[12]); h[13] = fast_tanh(P3.y + sB[13]);
    h[14] = fast_tanh(P3.z + sB[14]); h[15] = fast_tanh(P3.w + sB[15]);
    h[16] = fast_tanh(P4.x + sB[16]); h[17] = fast_tanh(P4.y + sB[17]);
    float g[9];
#pragma unroll
    for (int o = 0; o < 9; ++o) g[o] = sW[WP_B1 + o];
#pragma unroll
    for (int j = 0; j < 18; ++j) {
        float a = h[j];
#pragma unroll
        for (int o = 0; o < 9; ++o) g[o] += a * sW[WP_W1 + j * 9 + o];
    }
#pragma unroll
    for (int o = 0; o < 9; ++o) g[o] = fast_tanh(g[o]);
    float q[6];
#pragma unroll
    for (int o = 0; o < 6; ++o) q[o] = sW[WP_B2 + o];
#pragma unroll
    for (int j = 0; j < 9; ++j) {
        float a = g[j];
#pragma unroll
        for (int o = 0; o < 6; ++o) q[o] += a * sW[WP_W2 + j * 6 + o];
    }
#pragma unroll
    for (int o = 0; o < 6; ++o) q[o] = fast_tanh(q[o]);
    float o0 = sW[WP_B3 + 0], o1 = sW[WP_B3 + 1], o2 = sW[WP_B3 + 2];
#pragma unroll
    for (int j = 0; j < 6; ++j) {
        float a = q[j];
        o0 += a * sW[WP_W3 + j * 3 + 0];
        o1 += a * sW[WP_W3 + j * 3 + 1];
        o2 += a * sW[WP_W3 + j * 3 + 2];
    }
    p0 += o0; p1 += o1; p2 += o2;
}

__global__ void prep_kernel(const int* __restrict__ index,
                            const float* __restrict__ data,
                            const float* __restrict__ wf0, const float* __restrict__ bf0,
                            const float* __restrict__ sw0, const float* __restrict__ sb0,
                            const float* __restrict__ wf1, const float* __restrict__ bf1,
                            const float* __restrict__ wf2, const float* __restrict__ bf2,
                            const float* __restrict__ wf3, const float* __restrict__ bf3,
                            const float* __restrict__ sw1, const float* __restrict__ sb1,
                            const float* __restrict__ sw2, const float* __restrict__ sb2,
                            const float* __restrict__ sw3, const float* __restrict__ sb3,
                            float* __restrict__ wsp) {
    int i = blockIdx.x * blockDim.x + threadIdx.x;
    if (i < NROWS) {
        float d[7], cen[7];
#pragma unroll
        for (int c = 0; c < 7; ++c) d[c] = data[i * 7 + c];
        int ci = index[i];
#pragma unroll
        for (int c = 0; c < 7; ++c) cen[c] = data[ci * 7 + c];
#pragma unroll
        for (int j = 0; j < 18; ++j) {
            float af = 0.f;
#pragma unroll
            for (int c = 0; c < 7; ++c) af += d[c] * wf0[c * 18 + j];
            float as = d[0] * sw0[0 * 18 + j] + d[1] * sw0[1 * 18 + j] + d[2] * sw0[2 * 18 + j];
            float bf = bf0[j], bs = sb0[j];
#pragma unroll
            for (int c = 0; c < 3; ++c) bf -= cen[c] * wf0[c * 18 + j];
#pragma unroll
            for (int c = 0; c < 4; ++c) bf += cen[3 + c] * wf0[(7 + c) * 18 + j];
#pragma unroll
            for (int c = 0; c < 3; ++c) bs -= cen[c] * sw0[c * 18 + j];
#pragma unroll
            for (int c = 0; c < 4; ++c) bs += cen[3 + c] * sw0[(3 + c) * 18 + j];
            wsp[OFF_AF + i * 20 + j] = af;
            wsp[OFF_AS + i * 20 + j] = as;
            wsp[OFF_BF + i * 18 + j] = bf;
            wsp[OFF_BS + i * 18 + j] = bs;
        }
        wsp[OFF_AF + i * 20 + 18] = 0.f; wsp[OFF_AF + i * 20 + 19] = 0.f;
        wsp[OFF_AS + i * 20 + 18] = 0.f; wsp[OFF_AS + i * 20 + 19] = 0.f;
    }
    if (blockIdx.x == 0) {
        int t = threadIdx.x;
        float* wp = wsp + OFF_WP;
        for (int k = t; k < 162; k += 256) wp[WP_W1 + k] = wf1[k];
        for (int k = t; k < 9;   k += 256) wp[WP_B1 + k] = bf1[k];
        for (int k = t; k < 54;  k += 256) wp[WP_W2 + k] = wf2[k];
        for (int k = t; k < 6;   k += 256) wp[WP_B2 + k] = bf2[k];
        for (int k = t; k < 18;  k += 256) wp[WP_W3 + k] = wf3[k];
        for (int k = t; k < 3;   k += 256) wp[WP_B3 + k] = bf3[k];
        for (int k = t; k < 162; k += 256) wp[WP_SOLID + WP_W1 + k] = sw1[k];
        for (int k = t; k < 9;   k += 256) wp[WP_SOLID + WP_B1 + k] = sb1[k];
        for (int k = t; k < 54;  k += 256) wp[WP_SOLID + WP_W2 + k] = sw2[k];
        for (int k = t; k < 6;   k += 256) wp[WP_SOLID + WP_B2 + k] = sb2[k];
        for (int k = t; k < 18;  k += 256) wp[WP_SOLID + WP_W3 + k] = sw3[k];
        for (int k = t; k < 3;   k += 256) wp[WP_SOLID + WP_B3 + k] = sb3[k];
    }
}

__global__ __launch_bounds__(256)
void compact_kernel(const int* __restrict__ mask,
                    const float* __restrict__ data,
                    float* __restrict__ wsp) {
    const int lane = threadIdx.x & 63;
    const int n = blockIdx.x * 4 + (threadIdx.x >> 6);
    int* counts_f = (int*)(wsp + OFF_CF);
    int* counts_s = (int*)(wsp + OFF_CS);
    unsigned short* lf = (unsigned short*)(wsp + OFF_LISTS) + (size_t)n * MCOLS;
    unsigned short* ls = lf + LF_CAP;
    const int* mrow = mask + (size_t)n * MCOLS;
    int bf = 0, bs = 0;
    const unsigned long long ltmask = (1ull << lane) - 1ull;
#pragma unroll 1
    for (int it = 0; it < MCOLS / 64; ++it) {
        const int m = it * 64 + lane;
        const int mk = mrow[m];
        const float flag = data[m * 7 + 6];
        const bool af = mk && (flag > 0.f);
        const bool as = mk && (flag < 1.f);
        const unsigned long long balf = __ballot(af);
        const unsigned long long bals = __ballot(as);
        if (af) lf[bf + __popcll(balf & ltmask)] = (unsigned short)m;
        if (as) ls[bs + __popcll(bals & ltmask)] = (unsigned short)m;
        bf += __popcll(balf);
        bs += __popcll(bals);
    }
    if (lane == 0) { counts_f[n] = bf; counts_s[n] = bs; }
}

__global__ __launch_bounds__(256)
void main_kernel(const float* __restrict__ wsp, float* __restrict__ out) {
    const int n = blockIdx.x;
    const int tid = threadIdx.x;
    __shared__ float sW[504];
    __shared__ float sBf[18], sBs[18];
    __shared__ float red[3][4];
    for (int k = tid; k < 504; k += 256) sW[k] = wsp[OFF_WP + k];
    if (tid < 18) sBf[tid] = wsp[OFF_BF + n * 18 + tid];
    else if (tid < 36) sBs[tid - 18] = wsp[OFF_BS + n * 18 + (tid - 18)];
    __syncthreads();

    const int cf = ((const int*)(wsp + OFF_CF))[n];
    const int cs = ((const int*)(wsp + OFF_CS))[n];
    const unsigned short* lf = (const unsigned short*)(wsp + OFF_LISTS) + (size_t)n * MCOLS;
    const unsigned short* ls = lf + LF_CAP;
    const unsigned int* lf32 = (const unsigned int*)lf;
    const unsigned int* ls32 = (const unsigned int*)ls;

    float p0 = 0.f, p1 = 0.f, p2 = 0.f;
    const int npf = cf >> 1;
#pragma unroll 1
    for (int i = tid; i < npf; i += 256) {
        const unsigned int mm = lf32[i];
        mlp_pair(wsp + OFF_AF, (int)(mm & 0xffffu), (int)(mm >> 16), sBf, sW, p0, p1, p2);
    }
    if ((cf & 1) && tid == 0)
        mlp_one(wsp + OFF_AF, lf[cf - 1], sBf, sW, p0, p1, p2);

    const int nps = cs >> 1;
#pragma unroll 1
    for (int i = tid; i < nps; i += 256) {
        const unsigned int mm = ls32[i];
        mlp_pair(wsp + OFF_AS, (int)(mm & 0xffffu), (int)(mm >> 16), sBs, sW + WP_SOLID, p0, p1, p2);
    }
    if ((cs & 1) && tid == 0)
        mlp_one(wsp + OFF_AS, ls[cs - 1], sBs, sW + WP_SOLID, p0, p1, p2);

#pragma unroll
    for (int off = 32; off > 0; off >>= 1) {
        p0 += __shfl_xor(p0, off, 64);
        p1 += __shfl_xor(p1, off, 64);
        p2 += __shfl_xor(p2, off, 64);
    }
    const int wid = tid >> 6;
    if ((tid & 63) == 0) { red[0][wid] = p0; red[1][wid] = p1; red[2][wid] = p2; }
    __syncthreads();
    if (tid == 0) {
        float s0 = 0.f, s1 = 0.f, s2 = 0.f;
#pragma unroll
        for (int w = 0; w < 4; ++w) { s0 += red[0][w]; s1 += red[1][w]; s2 += red[2][w]; }
        out[n * 3 + 0] = s0; out[n * 3 + 1] = s1; out[n * 3 + 2] = s2;
    }
}

extern "C" void kernel_launch(void* const* d_in, const int* in_sizes, int n_in,
                              void* d_out, int out_size, void* d_ws, size_t ws_size,
                              hipStream_t stream) {
    const int*   mask  = (const int*)d_in[0];
    const int*   index = (const int*)d_in[1];
    const float* data  = (const float*)d_in[2];
    const float* wf0   = (const float*)d_in[3];
    const float* bf0   = (const float*)d_in[4];
    const float* wf1   = (const float*)d_in[5];
    const float* bf1   = (const float*)d_in[6];
    const float* wf2   = (const float*)d_in[7];
    const float* bf2   = (const float*)d_in[8];
    const float* wf3   = (const float*)d_in[9];
    const float* bf3   = (const float*)d_in[10];
    const float* sw0   = (const float*)d_in[11];
    const float* sb0   = (const float*)d_in[12];
    const float* sw1   = (const float*)d_in[13];
    const float* sb1   = (const float*)d_in[14];
    const float* sw2   = (const float*)d_in[15];
    const float* sb2   = (const float*)d_in[16];
    const float* sw3   = (const float*)d_in[17];
    const float* sb3   = (const float*)d_in[18];
    float* wsp = (float*)d_ws;
    float* out = (float*)d_out;

    prep_kernel<<<dim3(8), dim3(256), 0, stream>>>(
        index, data, wf0, bf0, sw0, sb0, wf1, bf1, wf2, bf2, wf3, bf3,
        sw1, sb1, sw2, sb2, sw3, sb3, wsp);
    compact_kernel<<<dim3(NROWS / 4), dim3(256), 0, stream>>>(mask, data, wsp);
    main_kernel<<<dim3(NROWS), dim3(256), 0, stream>>>(wsp, out);
}